// Round 13
// baseline (1127.824 us; speedup 1.0000x reference)
//
#include <hip/hip_runtime.h>

// ---------------- problem dims ----------------
#define IN_F  128
#define GHID  512
#define NHID  128
#define NTOK  196608L   // 1024 * 192
#define LDSP  520       // LDS row pitch in bf16 elems (512 + 8 pad)

#define L2E 1.4426950408889634f

typedef __attribute__((ext_vector_type(8))) short short8;
typedef __attribute__((ext_vector_type(4))) float floatx4;
typedef __attribute__((ext_vector_type(4))) float f4;

// ---------------- ws layout ----------------
// bf16 packed weights (ushort elems), 16x16x32 fragment order:
//   frag index = ((gate*(H/16) + tn) * (K/32) + tk), 512 elems per frag,
//   elem (lane,j): n = tn*16 + (lane&15), k = tk*32 + (lane>>4)*8 + j
#define O_GW0 0L
#define O_GW1 196608L
#define O_GW2 983040L
#define O_NW0 1769472L
#define O_NW1 1818624L
#define NWS   1867776L
// fp32 region (float elems), base byte = NWS*2
#define F_GB0 0
#define F_GB1 1536
#define F_GB2 3072
#define F_NB0 4608
#define F_NB1 4992
#define F_WE  5376
#define F_AW  5888
#define F_BE  6016
#define F_AB  6017

__device__ __forceinline__ unsigned short f2bf(float f) {
  unsigned int u = __float_as_uint(f);
  u += 0x7fffu + ((u >> 16) & 1u);      // RNE
  return (unsigned short)(u >> 16);
}

// ---------------- prep kernel: repack weights (NO prescale — R6 lesson) ----
__device__ __forceinline__ long srcoff(long pp, int H, int K) {
  long f = pp >> 9;
  int r = (int)(pp & 511);
  int ln = r >> 3, j = r & 7;
  int nKT = K >> 5, nCT = H >> 4;
  int tk = (int)(f % nKT);
  long t2 = f / nKT;
  int tn = (int)(t2 % nCT);
  int gate = (int)(t2 / nCT);
  int n = tn * 16 + (ln & 15);
  int k = tk * 32 + ((ln >> 4) << 3) + j;
  int go = (gate == 0) ? 0 : ((gate == 1) ? 2 * H : 3 * H);  // i, c, o rows
  return (long)(go + n) * K + k;
}

__global__ void prep_kernel(
    const float* __restrict__ gW0, const float* __restrict__ gbi0, const float* __restrict__ gbh0,
    const float* __restrict__ gW,  const float* __restrict__ gbi,  const float* __restrict__ gbh,
    const float* __restrict__ eW,  const float* __restrict__ eb,
    const float* __restrict__ nW0, const float* __restrict__ nbi0, const float* __restrict__ nbh0,
    const float* __restrict__ nW,  const float* __restrict__ nbi,  const float* __restrict__ nbh,
    const float* __restrict__ aW,  const float* __restrict__ ab,
    unsigned short* __restrict__ wpk, float* __restrict__ fpk)
{
  long idx = (long)blockIdx.x * blockDim.x + threadIdx.x;
  if (idx < NWS) {
    const float* src;
    long off;
    if (idx < O_GW1)      { off = srcoff(idx - O_GW0, 512, 128); src = gW0; }
    else if (idx < O_GW2) { off = srcoff(idx - O_GW1, 512, 512); src = gW; }
    else if (idx < O_NW0) { off = srcoff(idx - O_GW2, 512, 512); src = gW + 1048576; }
    else if (idx < O_NW1) { off = srcoff(idx - O_NW0, 128, 128); src = nW0; }
    else                  { off = srcoff(idx - O_NW1, 128, 128); src = nW; }
    wpk[idx] = f2bf(src[off]);
    return;
  }
  long p = idx - NWS;
  if (p < 1536) { int g = (int)(p >> 9), n = (int)(p & 511);
    int o = (g == 0 ? 0 : (g == 1 ? 1024 : 1536)) + n;
    fpk[F_GB0 + p] = gbi0[o] + gbh0[o]; return; }
  p -= 1536;
  if (p < 1536) { int g = (int)(p >> 9), n = (int)(p & 511);
    int o = (g == 0 ? 0 : (g == 1 ? 1024 : 1536)) + n;
    fpk[F_GB1 + p] = gbi[o] + gbh[o]; return; }
  p -= 1536;
  if (p < 1536) { int g = (int)(p >> 9), n = (int)(p & 511);
    int o = (g == 0 ? 0 : (g == 1 ? 1024 : 1536)) + n;
    fpk[F_GB2 + p] = gbi[2048 + o] + gbh[2048 + o]; return; }
  p -= 1536;
  if (p < 384) { int g = (int)(p / 128), n = (int)(p % 128);
    int o = (g == 0 ? 0 : (g == 1 ? 256 : 384)) + n;
    fpk[F_NB0 + p] = nbi0[o] + nbh0[o]; return; }
  p -= 384;
  if (p < 384) { int g = (int)(p / 128), n = (int)(p % 128);
    int o = (g == 0 ? 0 : (g == 1 ? 256 : 384)) + n;
    fpk[F_NB1 + p] = nbi[o] + nbh[o]; return; }
  p -= 384;
  if (p < 512) { float s = 0.f;
    for (int f = 0; f < 10; ++f) s += eW[f * 512 + p];
    fpk[F_WE + p] = s; return; }
  p -= 512;
  if (p < 128) { fpk[F_AW + p] = aW[p]; return; }
  p -= 128;
  if (p == 0) { float s = 0.f; for (int f = 0; f < 10; ++f) s += eb[f]; fpk[F_BE] = s; return; }
  if (p == 1) { fpk[F_AB] = ab[0]; return; }
}

// LSTM-cell combine from RAW gates (in-kernel scaling; prep stays byte-stable)
__device__ __forceinline__ float cell_h(float gi, float gc, float go) {
  float ei = __builtin_amdgcn_exp2f(gi * -L2E);
  float u  = __builtin_amdgcn_exp2f(gc * (2.0f * L2E));
  float eo = __builtin_amdgcn_exp2f(go * -L2E);
  float r1 = __builtin_amdgcn_rcpf((u + 1.f) * (1.f + ei));
  float cc = (u - 1.f) * r1;
  float s  = cc * cc;
  float num = cc * fmaf(10.f, s, 105.f);
  float den = fmaf(s, s + 45.f, 105.f);
  return num * __builtin_amdgcn_rcpf(den * (1.f + eo));
}

// ---------------- fused main kernel ----------------
// R13: NT=2 col-tiles share token A-fragments (halved LDS reads+conflicts,
// proven R12) at 4 waves/SIMD via TT=2 (acc stays 48 AGPR: NT*TT=4).
// Operand swap retained (weights = MFMA A operand, tokens = B operand):
// packed ushort4 h-writes, f4 bias fold, 1-deep weight rotation (R8/R10;
// deeper manual pipelines regressed — R11). Weight frags are read by 2 waves
// (token halves) in the same barrier epoch -> L1-hot duplicate.
template <int K, int H, int NT, int TT, int CPW, int CS, int TS, int MODE>
__device__ __forceinline__ void layer_run(
    const unsigned short* __restrict__ sIn,
    unsigned short* __restrict__ sOut,
    const unsigned short* __restrict__ wp,
    const float* __restrict__ bias,
    const float* __restrict__ dotw,
    float* accVec,
    int colTile0, int tokBase, int lane)
{
  constexpr int nKT = K / 32;
  constexpr int nCT = H / 16;
  constexpr size_t GS = (size_t)nCT * nKT * 512;   // gate stride (elems)
  const unsigned short* wl = wp + lane * 8;
  const unsigned short* aRow = sIn + (size_t)(tokBase + (lane & 15)) * LDSP + ((lane >> 4) << 3);

#pragma unroll
  for (int cp = 0; cp < CPW; ++cp) {
    const unsigned short* wb[NT];
    floatx4 acc[NT][3][TT];
#pragma unroll
    for (int t = 0; t < NT; ++t) {
      int tn = colTile0 + cp * CS + t * TS;
      wb[t] = wl + (size_t)tn * nKT * 512;
      int colBase = tn * 16 + ((lane >> 4) << 2);
      f4 bi4 = *(const f4*)(bias + colBase);
      f4 bc4 = *(const f4*)(bias + H + colBase);
      f4 bo4 = *(const f4*)(bias + 2 * H + colBase);
#pragma unroll
      for (int tt = 0; tt < TT; ++tt) {
        acc[t][0][tt] = (floatx4){bi4.x, bi4.y, bi4.z, bi4.w};
        acc[t][1][tt] = (floatx4){bc4.x, bc4.y, bc4.z, bc4.w};
        acc[t][2][tt] = (floatx4){bo4.x, bo4.y, bo4.z, bo4.w};
      }
    }
    // 1-deep weight rotation (global L2 loads)
    short8 wc[NT][3];
#pragma unroll
    for (int t = 0; t < NT; ++t)
#pragma unroll
      for (int g = 0; g < 3; ++g)
        wc[t][g] = *(const short8*)(wb[t] + g * GS);
#pragma unroll 1
    for (int ks = 0; ks < nKT; ++ks) {
      int nks = (ks + 1 < nKT) ? ks + 1 : ks;
      short8 wn[NT][3];
#pragma unroll
      for (int t = 0; t < NT; ++t)
#pragma unroll
        for (int g = 0; g < 3; ++g)
          wn[t][g] = *(const short8*)(wb[t] + g * GS + (size_t)nks * 512);
      short8 a[TT];
#pragma unroll
      for (int tt = 0; tt < TT; ++tt)
        a[tt] = *(const short8*)(aRow + (size_t)tt * 16 * LDSP + ks * 32);
#pragma unroll
      for (int tt = 0; tt < TT; ++tt)
#pragma unroll
        for (int t = 0; t < NT; ++t) {
          acc[t][0][tt] = __builtin_amdgcn_mfma_f32_16x16x32_bf16(wc[t][0], a[tt], acc[t][0][tt], 0, 0, 0);
          acc[t][1][tt] = __builtin_amdgcn_mfma_f32_16x16x32_bf16(wc[t][1], a[tt], acc[t][1][tt], 0, 0, 0);
          acc[t][2][tt] = __builtin_amdgcn_mfma_f32_16x16x32_bf16(wc[t][2], a[tt], acc[t][2][tt], 0, 0, 0);
        }
#pragma unroll
      for (int t = 0; t < NT; ++t)
#pragma unroll
        for (int g = 0; g < 3; ++g) wc[t][g] = wn[t][g];
    }
#pragma unroll
    for (int t = 0; t < NT; ++t) {
      int tn = colTile0 + cp * CS + t * TS;
      int colBase = tn * 16 + ((lane >> 4) << 2);
      f4 dw4;
      if constexpr (MODE == 1) dw4 = *(const f4*)(dotw + colBase);
#pragma unroll
      for (int tt = 0; tt < TT; ++tt) {
        int token = tokBase + tt * 16 + (lane & 15);
        if constexpr (MODE == 0) {
          ushort4 hw;
          hw.x = f2bf(cell_h(acc[t][0][tt][0], acc[t][1][tt][0], acc[t][2][tt][0]));
          hw.y = f2bf(cell_h(acc[t][0][tt][1], acc[t][1][tt][1], acc[t][2][tt][1]));
          hw.z = f2bf(cell_h(acc[t][0][tt][2], acc[t][1][tt][2], acc[t][2][tt][2]));
          hw.w = f2bf(cell_h(acc[t][0][tt][3], acc[t][1][tt][3], acc[t][2][tt][3]));
          *(ushort4*)&sOut[(size_t)token * LDSP + colBase] = hw;
        } else {
          float v = 0.f;
#pragma unroll
          for (int r = 0; r < 4; ++r) {
            float h = cell_h(acc[t][0][tt][r], acc[t][1][tt][r], acc[t][2][tt][r]);
            v = fmaf(fmaxf(h, 0.f), dw4[r], v);
          }
          v += __shfl_xor(v, 16);
          v += __shfl_xor(v, 32);
          if (lane < 16) atomicAdd(&accVec[token], v);
        }
      }
    }
  }
}

// 1024 threads = 16 waves = 4 waves/SIMD, 1 block/CU (LDS 133.6 KB).
// waves_per_eu(4,4): 128 unified regs/wave. acc 48 AGPR (NT2*TT2) + arch
// ~76 (wc 24 + wn 24 + a 8 + addr) -> fits. WRITE_SIZE is the spill sentinel.
__attribute__((amdgpu_waves_per_eu(4, 4)))
__global__ __launch_bounds__(1024) void dfrnn_main(
    const float* __restrict__ X,
    const unsigned short* __restrict__ wpk,
    const float* __restrict__ fpk,
    float* __restrict__ out)
{
  __shared__ __align__(16) unsigned short bufA[64 * LDSP];
  __shared__ __align__(16) unsigned short bufB[64 * LDSP];
  __shared__ float accMu[64];
  __shared__ float accSt[64];
  int tid = threadIdx.x;
  int wave = tid >> 6, lane = tid & 63;
  size_t blkTok = (size_t)blockIdx.x * 64;

  if (tid < 64) { accMu[tid] = 0.f; accSt[tid] = 0.f; }
  // load X tile [64 x 128] fp32 -> bf16, NON-TEMPORAL so streaming X doesn't
  // evict weights from L2 (R9/R10 evidence: FETCH 224 -> 73 MB)
  for (int i = tid; i < 64 * 32; i += 1024) {
    int row = i >> 5, c4 = i & 31;
    f4 v = __builtin_nontemporal_load((const f4*)(X + (blkTok + row) * 128 + c4 * 4));
    ushort4 b;
    b.x = f2bf(v.x); b.y = f2bf(v.y); b.z = f2bf(v.z); b.w = f2bf(v.w);
    *(ushort4*)&bufA[(size_t)row * LDSP + c4 * 4] = b;
  }
  __syncthreads();

  // noise L1: A[0..128) -> A[128..256); col tile = wave&7, half = wave>>3
  layer_run<128, 128, 1, 2, 1, 0, 0, 0>(bufA, bufA + 128, wpk + O_NW0, fpk + F_NB0,
                                        nullptr, nullptr, wave & 7, (wave >> 3) * 32, lane);
  __syncthreads();

  // noise L2: A[128..256) -> accSt (MODE 1); then global L1: A[0..128) -> B
  layer_run<128, 128, 1, 2, 1, 0, 0, 1>(bufA + 128, nullptr, wpk + O_NW1, fpk + F_NB1,
                                        fpk + F_AW, accSt, wave & 7, (wave >> 3) * 32, lane);
  // gL1: NT=2 (tiles (wave&7)+cp*16 and +8), CPW=2, token half = wave>>3
  layer_run<128, 512, 2, 2, 2, 16, 8, 0>(bufA, bufB, wpk + O_GW0, fpk + F_GB0,
                                         nullptr, nullptr, wave & 7, (wave >> 3) * 32, lane);
  __syncthreads();

  // global L2: B -> A (overwrites X + noise h, both dead)
  layer_run<512, 512, 2, 2, 2, 16, 8, 0>(bufB, bufA, wpk + O_GW1, fpk + F_GB1,
                                         nullptr, nullptr, wave & 7, (wave >> 3) * 32, lane);
  __syncthreads();

  // global L3: A -> accMu (relu-dot with w_e)
  layer_run<512, 512, 2, 2, 2, 16, 8, 1>(bufA, nullptr, wpk + O_GW2, fpk + F_GB2,
                                         fpk + F_WE, accMu, wave & 7, (wave >> 3) * 32, lane);
  __syncthreads();

  if (tid < 64) {
    float mu = accMu[tid] + fpk[F_BE];
    float st = accSt[tid] + fpk[F_AB];
    out[blkTok + tid] = mu;
    out[NTOK + blkTok + tid] = log1pf(__expf(st)) + 1e-6f;
  }
}

// ---------------- launch ----------------
extern "C" void kernel_launch(void* const* d_in, const int* in_sizes, int n_in,
                              void* d_out, int out_size, void* d_ws, size_t ws_size,
                              hipStream_t stream) {
  const float* X     = (const float*)d_in[0];
  const float* gW0   = (const float*)d_in[1];
  const float* gbi0  = (const float*)d_in[2];
  const float* gbh0  = (const float*)d_in[3];
  const float* gW    = (const float*)d_in[4];
  const float* gbi   = (const float*)d_in[5];
  const float* gbh   = (const float*)d_in[6];
  const float* eW    = (const float*)d_in[7];
  const float* eb    = (const float*)d_in[8];
  const float* nW0   = (const float*)d_in[9];
  const float* nbi0  = (const float*)d_in[10];
  const float* nbh0  = (const float*)d_in[11];
  const float* nW    = (const float*)d_in[12];
  const float* nbi   = (const float*)d_in[13];
  const float* nbh   = (const float*)d_in[14];
  const float* aW    = (const float*)d_in[15];
  const float* ab    = (const float*)d_in[16];

  unsigned short* wpk = (unsigned short*)d_ws;
  float* fpk = (float*)((char*)d_ws + NWS * 2);

  long prepTotal = NWS + 1536 * 3 + 384 * 2 + 512 + 128 + 2;
  int prepBlocks = (int)((prepTotal + 255) / 256);
  prep_kernel<<<prepBlocks, 256, 0, stream>>>(gW0, gbi0, gbh0, gW, gbi, gbh, eW, eb,
                                              nW0, nbi0, nbh0, nW, nbi, nbh, aW, ab,
                                              wpk, fpk);
  dfrnn_main<<<3072, 1024, 0, stream>>>(X, wpk, fpk, (float*)d_out);
}

// Round 14
// 914.092 us; speedup vs baseline: 1.2338x; 1.2338x over previous
//
#include <hip/hip_runtime.h>

// ---------------- problem dims ----------------
#define IN_F  128
#define GHID  512
#define NHID  128
#define NTOK  196608L   // 1024 * 192
#define LDSP  520       // global LDS row pitch (512 + 8 pad)
#define NPITCH 136      // noise-h1 LDS row pitch (128 + 8 pad)

#define L2E 1.4426950408889634f

typedef __attribute__((ext_vector_type(8))) short short8;
typedef __attribute__((ext_vector_type(4))) float floatx4;
typedef __attribute__((ext_vector_type(4))) float f4;

// ---------------- ws layout ----------------
// bf16 packed weights (ushort elems), 16x16x32 fragment order:
//   frag index = ((gate*(H/16) + tn) * (K/32) + tk), 512 elems per frag,
//   elem (lane,j): n = tn*16 + (lane&15), k = tk*32 + (lane>>4)*8 + j
#define O_GW0 0L
#define O_GW1 196608L
#define O_GW2 983040L
#define O_NW0 1769472L
#define O_NW1 1818624L
#define NWS   1867776L
// fp32 region (float elems), base byte = NWS*2
#define F_GB0 0
#define F_GB1 1536
#define F_GB2 3072
#define F_NB0 4608
#define F_NB1 4992
#define F_WE  5376
#define F_AW  5888
#define F_BE  6016
#define F_AB  6017

__device__ __forceinline__ unsigned short f2bf(float f) {
  unsigned int u = __float_as_uint(f);
  u += 0x7fffu + ((u >> 16) & 1u);      // RNE
  return (unsigned short)(u >> 16);
}

// ---------------- prep kernel: repack weights (NO prescale — R6 lesson) ----
__device__ __forceinline__ long srcoff(long pp, int H, int K) {
  long f = pp >> 9;
  int r = (int)(pp & 511);
  int ln = r >> 3, j = r & 7;
  int nKT = K >> 5, nCT = H >> 4;
  int tk = (int)(f % nKT);
  long t2 = f / nKT;
  int tn = (int)(t2 % nCT);
  int gate = (int)(t2 / nCT);
  int n = tn * 16 + (ln & 15);
  int k = tk * 32 + ((ln >> 4) << 3) + j;
  int go = (gate == 0) ? 0 : ((gate == 1) ? 2 * H : 3 * H);  // i, c, o rows
  return (long)(go + n) * K + k;
}

__global__ void prep_kernel(
    const float* __restrict__ gW0, const float* __restrict__ gbi0, const float* __restrict__ gbh0,
    const float* __restrict__ gW,  const float* __restrict__ gbi,  const float* __restrict__ gbh,
    const float* __restrict__ eW,  const float* __restrict__ eb,
    const float* __restrict__ nW0, const float* __restrict__ nbi0, const float* __restrict__ nbh0,
    const float* __restrict__ nW,  const float* __restrict__ nbi,  const float* __restrict__ nbh,
    const float* __restrict__ aW,  const float* __restrict__ ab,
    unsigned short* __restrict__ wpk, float* __restrict__ fpk)
{
  long idx = (long)blockIdx.x * blockDim.x + threadIdx.x;
  if (idx < NWS) {
    const float* src;
    long off;
    if (idx < O_GW1)      { off = srcoff(idx - O_GW0, 512, 128); src = gW0; }
    else if (idx < O_GW2) { off = srcoff(idx - O_GW1, 512, 512); src = gW; }
    else if (idx < O_NW0) { off = srcoff(idx - O_GW2, 512, 512); src = gW + 1048576; }
    else if (idx < O_NW1) { off = srcoff(idx - O_NW0, 128, 128); src = nW0; }
    else                  { off = srcoff(idx - O_NW1, 128, 128); src = nW; }
    wpk[idx] = f2bf(src[off]);
    return;
  }
  long p = idx - NWS;
  if (p < 1536) { int g = (int)(p >> 9), n = (int)(p & 511);
    int o = (g == 0 ? 0 : (g == 1 ? 1024 : 1536)) + n;
    fpk[F_GB0 + p] = gbi0[o] + gbh0[o]; return; }
  p -= 1536;
  if (p < 1536) { int g = (int)(p >> 9), n = (int)(p & 511);
    int o = (g == 0 ? 0 : (g == 1 ? 1024 : 1536)) + n;
    fpk[F_GB1 + p] = gbi[o] + gbh[o]; return; }
  p -= 1536;
  if (p < 1536) { int g = (int)(p >> 9), n = (int)(p & 511);
    int o = (g == 0 ? 0 : (g == 1 ? 1024 : 1536)) + n;
    fpk[F_GB2 + p] = gbi[2048 + o] + gbh[2048 + o]; return; }
  p -= 1536;
  if (p < 384) { int g = (int)(p / 128), n = (int)(p % 128);
    int o = (g == 0 ? 0 : (g == 1 ? 256 : 384)) + n;
    fpk[F_NB0 + p] = nbi0[o] + nbh0[o]; return; }
  p -= 384;
  if (p < 384) { int g = (int)(p / 128), n = (int)(p % 128);
    int o = (g == 0 ? 0 : (g == 1 ? 256 : 384)) + n;
    fpk[F_NB1 + p] = nbi[o] + nbh[o]; return; }
  p -= 384;
  if (p < 512) { float s = 0.f;
    for (int f = 0; f < 10; ++f) s += eW[f * 512 + p];
    fpk[F_WE + p] = s; return; }
  p -= 512;
  if (p < 128) { fpk[F_AW + p] = aW[p]; return; }
  p -= 128;
  if (p == 0) { float s = 0.f; for (int f = 0; f < 10; ++f) s += eb[f]; fpk[F_BE] = s; return; }
  if (p == 1) { fpk[F_AB] = ab[0]; return; }
}

// LSTM-cell combine from RAW gates (in-kernel scaling; prep stays byte-stable)
__device__ __forceinline__ float cell_h(float gi, float gc, float go) {
  float ei = __builtin_amdgcn_exp2f(gi * -L2E);
  float u  = __builtin_amdgcn_exp2f(gc * (2.0f * L2E));
  float eo = __builtin_amdgcn_exp2f(go * -L2E);
  float r1 = __builtin_amdgcn_rcpf((u + 1.f) * (1.f + ei));
  float cc = (u - 1.f) * r1;
  float s  = cc * cc;
  float num = cc * fmaf(10.f, s, 105.f);
  float den = fmaf(s, s + 45.f, 105.f);
  return num * __builtin_amdgcn_rcpf(den * (1.f + eo));
}

// ---------------- fused main kernel ----------------
// R10 engine (823 us, best): operand swap (weights = MFMA A operand, tokens =
// B operand; packed ushort4 h-writes; f4 bias fold), 1-deep B rotation, batched
// token A-reads, unroll-1 ks loop. R14 adds pitch params (PI/PO) so noise h1
// lives in its own 17 KB buffer -> nL1||gL1 and nL2||gL2 merge into 2 epochs.
template <int K, int H, int TT, int CPW, int NW, int MODE, int PI, int PO>
__device__ __forceinline__ void layer_run(
    const unsigned short* __restrict__ sIn,
    unsigned short* __restrict__ sOut,
    const unsigned short* __restrict__ wp,
    const float* __restrict__ bias,
    const float* __restrict__ dotw,
    float* accVec,
    int colTile0, int tokBase, int lane)
{
  constexpr int nKT = K / 32;
  constexpr int nCT = H / 16;
#pragma unroll
  for (int cp = 0; cp < CPW; ++cp) {
    int tn = colTile0 + cp * NW;
    int colBase = tn * 16 + ((lane >> 4) << 2);   // 4 consecutive outcols/lane
    const unsigned short* p0 = wp + (size_t)tn * nKT * 512 + lane * 8;
    const unsigned short* p1 = p0 + (size_t)nCT * nKT * 512;
    const unsigned short* p2 = p1 + (size_t)nCT * nKT * 512;
    short8 b0 = *(const short8*)(p0);
    short8 b1 = *(const short8*)(p1);
    short8 b2 = *(const short8*)(p2);
    f4 bi4 = *(const f4*)(bias + colBase);
    f4 bc4 = *(const f4*)(bias + H + colBase);
    f4 bo4 = *(const f4*)(bias + 2 * H + colBase);
    floatx4 acc[3][TT];
#pragma unroll
    for (int tt = 0; tt < TT; ++tt) {
      acc[0][tt] = (floatx4){bi4.x, bi4.y, bi4.z, bi4.w};
      acc[1][tt] = (floatx4){bc4.x, bc4.y, bc4.z, bc4.w};
      acc[2][tt] = (floatx4){bo4.x, bo4.y, bo4.z, bo4.w};
    }
    const unsigned short* aRow = sIn + (size_t)(tokBase + (lane & 15)) * PI + ((lane >> 4) << 3);
#pragma unroll 1
    for (int ks = 0; ks < nKT; ++ks) {
      int nks = (ks + 1 < nKT) ? (ks + 1) : ks;
      short8 nb0 = *(const short8*)(p0 + (size_t)nks * 512);
      short8 nb1 = *(const short8*)(p1 + (size_t)nks * 512);
      short8 nb2 = *(const short8*)(p2 + (size_t)nks * 512);
      short8 a[TT];
#pragma unroll
      for (int tt = 0; tt < TT; ++tt)
        a[tt] = *(const short8*)(aRow + (size_t)tt * 16 * PI + ks * 32);
#pragma unroll
      for (int tt = 0; tt < TT; ++tt) {
        // A = weights (rows -> outcols), B = tokens (cols -> tokens)
        acc[0][tt] = __builtin_amdgcn_mfma_f32_16x16x32_bf16(b0, a[tt], acc[0][tt], 0, 0, 0);
        acc[1][tt] = __builtin_amdgcn_mfma_f32_16x16x32_bf16(b1, a[tt], acc[1][tt], 0, 0, 0);
        acc[2][tt] = __builtin_amdgcn_mfma_f32_16x16x32_bf16(b2, a[tt], acc[2][tt], 0, 0, 0);
      }
      b0 = nb0; b1 = nb1; b2 = nb2;
    }
    f4 dw4;
    if constexpr (MODE == 1) dw4 = *(const f4*)(dotw + colBase);
#pragma unroll
    for (int tt = 0; tt < TT; ++tt) {
      int token = tokBase + tt * 16 + (lane & 15);
      if constexpr (MODE == 0) {
        ushort4 hw;
        hw.x = f2bf(cell_h(acc[0][tt][0], acc[1][tt][0], acc[2][tt][0]));
        hw.y = f2bf(cell_h(acc[0][tt][1], acc[1][tt][1], acc[2][tt][1]));
        hw.z = f2bf(cell_h(acc[0][tt][2], acc[1][tt][2], acc[2][tt][2]));
        hw.w = f2bf(cell_h(acc[0][tt][3], acc[1][tt][3], acc[2][tt][3]));
        *(ushort4*)&sOut[(size_t)token * PO + colBase] = hw;
      } else {
        float v = 0.f;
#pragma unroll
        for (int r = 0; r < 4; ++r) {
          float h = cell_h(acc[0][tt][r], acc[1][tt][r], acc[2][tt][r]);
          v = fmaf(fmaxf(h, 0.f), dw4[r], v);
        }
        v += __shfl_xor(v, 16);
        v += __shfl_xor(v, 32);
        if (lane < 16) atomicAdd(&accVec[token], v);
      }
    }
  }
}

// 1024 threads = 16 waves = 4 waves/SIMD, 1 block/CU (LDS 151 KB).
// waves_per_eu(4,4): 128 unified regs/wave (~52 arch + 48 acc, proven R10).
// Epochs: E1 load X | E2 nL1||gL1 | E3 nL2||gL2 | E4 gL3 | out.
__attribute__((amdgpu_waves_per_eu(4, 4)))
__global__ __launch_bounds__(1024) void dfrnn_main(
    const float* __restrict__ X,
    const unsigned short* __restrict__ wpk,
    const float* __restrict__ fpk,
    float* __restrict__ out)
{
  __shared__ __align__(16) unsigned short bufA[64 * LDSP];
  __shared__ __align__(16) unsigned short bufB[64 * LDSP];
  __shared__ __align__(16) unsigned short bufN[64 * NPITCH];
  __shared__ float accMu[64];
  __shared__ float accSt[64];
  int tid = threadIdx.x;
  int wave = tid >> 6, lane = tid & 63;
  size_t blkTok = (size_t)blockIdx.x * 64;

  if (tid < 64) { accMu[tid] = 0.f; accSt[tid] = 0.f; }
  // E1: load X tile [64 x 128] fp32 -> bf16, NON-TEMPORAL so streaming X
  // doesn't evict L2-resident weights (R9/R10 evidence: FETCH 224 -> 73 MB)
  for (int i = tid; i < 64 * 32; i += 1024) {
    int row = i >> 5, c4 = i & 31;
    f4 v = __builtin_nontemporal_load((const f4*)(X + (blkTok + row) * 128 + c4 * 4));
    ushort4 b;
    b.x = f2bf(v.x); b.y = f2bf(v.y); b.z = f2bf(v.z); b.w = f2bf(v.w);
    *(ushort4*)&bufA[(size_t)row * LDSP + c4 * 4] = b;
  }
  __syncthreads();

  // E2: noise L1 (A[0:128) -> N) and global L1 (A[0:128) -> B) — disjoint
  // writes, shared input, one barrier epoch.
  layer_run<128, 128, 2, 1, 8, 0, LDSP, NPITCH>(bufA, bufN, wpk + O_NW0, fpk + F_NB0,
                                                nullptr, nullptr, wave & 7, (wave >> 3) * 32, lane);
  layer_run<128, 512, 4, 2, 16, 0, LDSP, LDSP>(bufA, bufB, wpk + O_GW0, fpk + F_GB0,
                                               nullptr, nullptr, wave, 0, lane);
  __syncthreads();

  // E3: noise L2 (N -> accSt) and global L2 (B -> A; A's old contents dead,
  // noise h1 now lives in N so no read/write overlap).
  layer_run<128, 128, 2, 1, 8, 1, NPITCH, NPITCH>(bufN, nullptr, wpk + O_NW1, fpk + F_NB1,
                                                  fpk + F_AW, accSt, wave & 7, (wave >> 3) * 32, lane);
  layer_run<512, 512, 4, 2, 16, 0, LDSP, LDSP>(bufB, bufA, wpk + O_GW1, fpk + F_GB1,
                                               nullptr, nullptr, wave, 0, lane);
  __syncthreads();

  // E4: global L3 (A -> accMu, relu-dot with w_e)
  layer_run<512, 512, 4, 2, 16, 1, LDSP, LDSP>(bufA, nullptr, wpk + O_GW2, fpk + F_GB2,
                                               fpk + F_WE, accMu, wave, 0, lane);
  __syncthreads();

  if (tid < 64) {
    float mu = accMu[tid] + fpk[F_BE];
    float st = accSt[tid] + fpk[F_AB];
    out[blkTok + tid] = mu;
    out[NTOK + blkTok + tid] = log1pf(__expf(st)) + 1e-6f;
  }
}

// ---------------- launch ----------------
extern "C" void kernel_launch(void* const* d_in, const int* in_sizes, int n_in,
                              void* d_out, int out_size, void* d_ws, size_t ws_size,
                              hipStream_t stream) {
  const float* X     = (const float*)d_in[0];
  const float* gW0   = (const float*)d_in[1];
  const float* gbi0  = (const float*)d_in[2];
  const float* gbh0  = (const float*)d_in[3];
  const float* gW    = (const float*)d_in[4];
  const float* gbi   = (const float*)d_in[5];
  const float* gbh   = (const float*)d_in[6];
  const float* eW    = (const float*)d_in[7];
  const float* eb    = (const float*)d_in[8];
  const float* nW0   = (const float*)d_in[9];
  const float* nbi0  = (const float*)d_in[10];
  const float* nbh0  = (const float*)d_in[11];
  const float* nW    = (const float*)d_in[12];
  const float* nbi   = (const float*)d_in[13];
  const float* nbh   = (const float*)d_in[14];
  const float* aW    = (const float*)d_in[15];
  const float* ab    = (const float*)d_in[16];

  unsigned short* wpk = (unsigned short*)d_ws;
  float* fpk = (float*)((char*)d_ws + NWS * 2);

  long prepTotal = NWS + 1536 * 3 + 384 * 2 + 512 + 128 + 2;
  int prepBlocks = (int)((prepTotal + 255) / 256);
  prep_kernel<<<prepBlocks, 256, 0, stream>>>(gW0, gbi0, gbh0, gW, gbi, gbh, eW, eb,
                                              nW0, nbi0, nbh0, nW, nbi, nbh, aW, ab,
                                              wpk, fpk);
  dfrnn_main<<<3072, 1024, 0, stream>>>(X, wpk, fpk, (float*)d_out);
}